// Round 1
// baseline (424.196 us; speedup 1.0000x reference)
//
#include <hip/hip_runtime.h>
#include <hip/hip_bf16.h>

// DoReFa conv2d, MI355X.
// xq = round(min(1,|x|)*7)/7  -> integer k in 0..7, exact in bf16
// wq = sign(W)*E, E = mean|W| -> sign in {-1,0,+1}, exact in bf16
// y[p,c] = (E/7) * sum_k( sign * k ) + b[c]   (integer sum exact in fp32 acc)
// Implicit GEMM via mfma_f32_16x16x32_bf16: M=pixels, N=32 ch, K=144 (padded to 160).

typedef __bf16 bf16x8 __attribute__((ext_vector_type(8)));
typedef float f32x4 __attribute__((ext_vector_type(4)));

#define TW 32   // output tile width  (x)
#define TH 16   // output tile height (y)
#define LW 34   // input tile width with halo
#define LH 18   // input tile height with halo
#define PST 48  // bytes per pixel in LDS (16ch * bf16 = 32B, +16 pad => conflict-free b128 reads)

__device__ __forceinline__ unsigned short quant3(float v) {
  // k = rint(min(1,|v|)*7)  in {0..7}; bf16 bits = fp32 bits >> 16 (exact for small ints)
  float t = rintf(fminf(fabsf(v), 1.0f) * 7.0f);
  union { float f; unsigned int u; } cv; cv.f = t;
  return (unsigned short)(cv.u >> 16);
}

// One block: computes E = mean|W|, writes scale = E/7 to ws[0], and the
// MFMA B-operand sign table (bf16) at ws+16B, layout [pair 5][nf 2][lane 64][j 8].
// For pair p<4: positions 2p,2p+1 (k-groups g=0,1 -> pos 2p ci 0..15; g=2,3 -> pos 2p+1).
// For p==4: pos 8 in g=0,1; zeros in g=2,3 (K padding).
__global__ void prep_kernel(const float* __restrict__ W, float* __restrict__ ws) {
  __shared__ float red[256];
  int tid = threadIdx.x;
  float s = 0.f;
  for (int i = tid; i < 4608; i += 256) s += fabsf(W[i]);
  red[tid] = s;
  __syncthreads();
  for (int off = 128; off > 0; off >>= 1) {
    if (tid < off) red[tid] += red[tid + off];
    __syncthreads();
  }
  float E = red[0] * (1.0f / 4608.0f);
  if (tid == 0) ws[0] = E * (1.0f / 7.0f);
  unsigned short* bf = (unsigned short*)(ws + 4);
  for (int i = tid; i < 5 * 2 * 64 * 8; i += 256) {
    int j  = i & 7;
    int l  = (i >> 3) & 63;
    int nf = (i >> 9) & 1;
    int p  = i >> 10;
    int g  = l >> 4;
    float v = 0.f;
    if (p < 4 || g < 2) {
      int pos = (p < 4) ? (2 * p + (g >> 1)) : 8;   // kh*3+kw
      int ci  = (g & 1) * 8 + j;
      int c   = nf * 16 + (l & 15);
      float w = W[(pos * 16 + ci) * 32 + c];        // W[kh][kw][ci][c]
      v = (w > 0.f) ? 1.f : ((w < 0.f) ? -1.f : 0.f);
    }
    union { float f; unsigned int u; } cv; cv.f = v;
    bf[i] = (unsigned short)(cv.u >> 16);
  }
}

__global__ __launch_bounds__(256, 4) void conv_kernel(
    const float* __restrict__ x, const float* __restrict__ bias,
    const float* __restrict__ ws, float* __restrict__ out) {
  __shared__ __align__(16) char lds[LH * LW * PST];  // 29376 B
  const unsigned short* bfr = (const unsigned short*)(ws + 4);

  int bid = blockIdx.x;
  int tile_x = bid & 15;          // 512/32 = 16 x-tiles
  int tile_y = (bid >> 4) & 31;   // 512/16 = 32 y-tiles
  int n      = bid >> 9;          // 8 images
  int gx0 = tile_x * TW, gy0 = tile_y * TH;
  int tid  = threadIdx.x;
  int lane = tid & 63;
  int wv   = tid >> 6;            // wave 0..3, owns rows wv*4 .. wv*4+3
  int g    = lane >> 4;           // k-group (A) / row-group (D)
  int m    = lane & 15;           // A row (pixel-in-Mtile) / D col (channel)

  // Preload B fragments (sign table) — uniform across blocks, L2/L3-served.
  bf16x8 bfrag[5][2];
#pragma unroll
  for (int p = 0; p < 5; ++p)
#pragma unroll
    for (int nf = 0; nf < 2; ++nf)
      bfrag[p][nf] = *(const bf16x8*)(bfr + ((p * 2 + nf) * 64 + lane) * 8);
  float scale = ws[0];
  float b0 = bias[m], b1 = bias[m + 16];

  // Stage quantized input tile (with halo, zero-padded) into LDS.
  const float* xn = x + (size_t)n * (512 * 512 * 16);
  for (int i = tid; i < LH * LW * 4; i += 256) {
    int cig = i & 3;         // channel group of 4
    int pix = i >> 2;        // 0..611
    int py = pix / LW;
    int px = pix - py * LW;
    int gy = gy0 - 1 + py, gx = gx0 - 1 + px;
    float4 v = make_float4(0.f, 0.f, 0.f, 0.f);
    if (gy >= 0 && gy < 512 && gx >= 0 && gx < 512)
      v = *(const float4*)(xn + ((gy << 9) + gx) * 16 + cig * 4);
    ushort4 q;
    q.x = quant3(v.x); q.y = quant3(v.y); q.z = quant3(v.z); q.w = quant3(v.w);
    *(ushort4*)(&lds[pix * PST + cig * 8]) = q;
  }

  // Per-lane LDS offsets for the 5 K-pairs of the A operand.
  int laneoff[5];
#pragma unroll
  for (int p = 0; p < 5; ++p) {
    int pos = (p < 4) ? (2 * p + (g >> 1)) : 8;
    int kh = pos / 3, kw = pos - kh * 3;
    laneoff[p] = (kh * LW + kw) * PST + (g & 1) * 16 + m * PST;
  }

  __syncthreads();

#pragma unroll
  for (int r = 0; r < 4; ++r) {
    int ty = wv * 4 + r;
#pragma unroll
    for (int xt = 0; xt < 2; ++xt) {
      int tx = xt * 16;
      int base = (ty * LW + tx) * PST;
      f32x4 acc0 = {0.f, 0.f, 0.f, 0.f};
      f32x4 acc1 = {0.f, 0.f, 0.f, 0.f};
#pragma unroll
      for (int p = 0; p < 5; ++p) {
        bf16x8 a = *(const bf16x8*)(&lds[base + laneoff[p]]);
        acc0 = __builtin_amdgcn_mfma_f32_16x16x32_bf16(a, bfrag[p][0], acc0, 0, 0, 0);
        acc1 = __builtin_amdgcn_mfma_f32_16x16x32_bf16(a, bfrag[p][1], acc1, 0, 0, 0);
      }
      // D layout: col = lane&15 (channel), row = (lane>>4)*4 + j (pixel x offset)
      size_t obase = (((size_t)((n << 9) + (gy0 + ty)) << 9) + (gx0 + tx + (g << 2))) * 32 + m;
#pragma unroll
      for (int j = 0; j < 4; ++j) {
        out[obase + (size_t)j * 32]      = acc0[j] * scale + b0;
        out[obase + (size_t)j * 32 + 16] = acc1[j] * scale + b1;
      }
    }
  }
}

extern "C" void kernel_launch(void* const* d_in, const int* in_sizes, int n_in,
                              void* d_out, int out_size, void* d_ws, size_t ws_size,
                              hipStream_t stream) {
  const float* x = (const float*)d_in[0];
  const float* W = (const float*)d_in[1];
  const float* b = (const float*)d_in[2];
  float* out = (float*)d_out;
  float* ws  = (float*)d_ws;

  prep_kernel<<<1, 256, 0, stream>>>(W, ws);
  conv_kernel<<<4096, 256, 0, stream>>>(x, b, ws, out);
}

// Round 2
// 392.667 us; speedup vs baseline: 1.0803x; 1.0803x over previous
//
#include <hip/hip_runtime.h>
#include <hip/hip_bf16.h>

// DoReFa conv2d, MI355X.
// xq = round(min(1,|x|)*7)/7  -> integer k in 0..7, exact in bf16
// wq = sign(W)*E, E = mean|W| -> sign in {-1,0,+1}, exact in bf16
// y[p,c] = (E/7) * sum_k( sign * k ) + b[c]   (integer sum exact in fp32 acc)
// Implicit GEMM via mfma_f32_16x16x32_bf16, weights as A operand, pixels as B:
// D[row=channel][col=pixel] -> per-lane float4 stores over 4 consecutive channels.

typedef __bf16 bf16x8 __attribute__((ext_vector_type(8)));
typedef float f32x4 __attribute__((ext_vector_type(4)));

#define TW 32   // output tile width  (x)
#define TH 16   // output tile height (y)
#define LW 34   // input tile width with halo
#define LH 18   // input tile height with halo
#define PST 48  // bytes per pixel in LDS (16ch * bf16 = 32B, +16 pad)

__device__ __forceinline__ unsigned short quant3(float v) {
  // k = rint(min(1,|v|)*7)  in {0..7}; bf16 bits = fp32 bits >> 16 (exact for small ints)
  float t = rintf(fminf(fabsf(v), 1.0f) * 7.0f);
  union { float f; unsigned int u; } cv; cv.f = t;
  return (unsigned short)(cv.u >> 16);
}

// One block: computes E = mean|W|, writes scale = E/7 to ws[0], and the
// MFMA weight-operand sign table (bf16) at ws+16B, layout [pair 5][nf 2][lane 64][j 8].
// Lane l holds matrix-dim index (l&15) = output channel (+16*nf), k-group g = l>>4:
// pair p<4: pos = 2p + (g>>1), ci = (g&1)*8 + j. pair 4: pos 8 for g<2, zeros g>=2.
// (Identical packing for A- and B-operand roles on mfma_f32_16x16x32_bf16.)
__global__ void prep_kernel(const float* __restrict__ W, float* __restrict__ ws) {
  __shared__ float red[256];
  int tid = threadIdx.x;
  float s = 0.f;
  for (int i = tid; i < 4608; i += 256) s += fabsf(W[i]);
  red[tid] = s;
  __syncthreads();
  for (int off = 128; off > 0; off >>= 1) {
    if (tid < off) red[tid] += red[tid + off];
    __syncthreads();
  }
  float E = red[0] * (1.0f / 4608.0f);
  if (tid == 0) ws[0] = E * (1.0f / 7.0f);
  unsigned short* bf = (unsigned short*)(ws + 4);
  for (int i = tid; i < 5 * 2 * 64 * 8; i += 256) {
    int j  = i & 7;
    int l  = (i >> 3) & 63;
    int nf = (i >> 9) & 1;
    int p  = i >> 10;
    int g  = l >> 4;
    float v = 0.f;
    if (p < 4 || g < 2) {
      int pos = (p < 4) ? (2 * p + (g >> 1)) : 8;   // kh*3+kw
      int ci  = (g & 1) * 8 + j;
      int c   = nf * 16 + (l & 15);
      float w = W[(pos * 16 + ci) * 32 + c];        // W[kh][kw][ci][c]
      v = (w > 0.f) ? 1.f : ((w < 0.f) ? -1.f : 0.f);
    }
    union { float f; unsigned int u; } cv; cv.f = v;
    bf[i] = (unsigned short)(cv.u >> 16);
  }
}

__global__ __launch_bounds__(256) void conv_kernel(
    const float* __restrict__ x, const float* __restrict__ bias,
    const float* __restrict__ ws, float* __restrict__ out) {
  __shared__ __align__(16) char lds[LH * LW * PST];  // 29376 B
  const unsigned short* bfr = (const unsigned short*)(ws + 4);

  int bid = blockIdx.x;
  int tile_x = bid & 15;          // 512/32 = 16 x-tiles
  int tile_y = (bid >> 4) & 31;   // 512/16 = 32 y-tiles
  int n      = bid >> 9;          // 8 images
  int gx0 = tile_x * TW, gy0 = tile_y * TH;
  int tid  = threadIdx.x;
  int lane = tid & 63;
  int wv   = tid >> 6;            // wave 0..3, owns rows wv*4 .. wv*4+3
  int g    = lane >> 4;           // k-group (operands) / channel-group (D)
  int m    = lane & 15;           // matrix-dim index: weight-chan (A) / pixel (B, D col)

  // Preload weight fragments (sign table) — uniform across blocks, L2/L3-served.
  bf16x8 bfrag[5][2];
#pragma unroll
  for (int p = 0; p < 5; ++p)
#pragma unroll
    for (int nf = 0; nf < 2; ++nf)
      bfrag[p][nf] = *(const bf16x8*)(bfr + ((p * 2 + nf) * 64 + lane) * 8);
  float scale = ws[0];
  float4 bias0 = ((const float4*)bias)[g];       // channels 4g..4g+3
  float4 bias1 = ((const float4*)bias)[g + 4];   // channels 16+4g..16+4g+3

  // Stage quantized input tile (with halo, zero-padded) into LDS.
  const float* xn = x + (size_t)n * (512 * 512 * 16);
  for (int i = tid; i < LH * LW * 4; i += 256) {
    int cig = i & 3;         // channel group of 4
    int pix = i >> 2;        // 0..611
    int py = pix / LW;
    int px = pix - py * LW;
    int gy = gy0 - 1 + py, gx = gx0 - 1 + px;
    float4 v = make_float4(0.f, 0.f, 0.f, 0.f);
    if (gy >= 0 && gy < 512 && gx >= 0 && gx < 512)
      v = *(const float4*)(xn + ((gy << 9) + gx) * 16 + cig * 4);
    ushort4 q;
    q.x = quant3(v.x); q.y = quant3(v.y); q.z = quant3(v.z); q.w = quant3(v.w);
    *(ushort4*)(&lds[pix * PST + cig * 8]) = q;
  }

  // Per-lane LDS offsets for the 5 K-pairs of the pixel (B) operand.
  // B col = m -> pixel x = tx + m; k-group g -> (pos, ci): pos=2p+(g>>1) (p<4), 8 (p==4).
  int laneoff[5];
#pragma unroll
  for (int p = 0; p < 5; ++p) {
    int pos = (p < 4) ? (2 * p + (g >> 1)) : 8;
    int kh = pos / 3, kw = pos - kh * 3;
    laneoff[p] = (kh * LW + kw) * PST + (g & 1) * 16 + m * PST;
  }

  __syncthreads();

#pragma unroll
  for (int r = 0; r < 4; ++r) {
    int ty = wv * 4 + r;
#pragma unroll
    for (int xt = 0; xt < 2; ++xt) {
      int tx = xt * 16;
      int base = (ty * LW + tx) * PST;
      f32x4 acc0 = {0.f, 0.f, 0.f, 0.f};
      f32x4 acc1 = {0.f, 0.f, 0.f, 0.f};
#pragma unroll
      for (int p = 0; p < 5; ++p) {
        bf16x8 b = *(const bf16x8*)(&lds[base + laneoff[p]]);
        acc0 = __builtin_amdgcn_mfma_f32_16x16x32_bf16(bfrag[p][0], b, acc0, 0, 0, 0);
        acc1 = __builtin_amdgcn_mfma_f32_16x16x32_bf16(bfrag[p][1], b, acc1, 0, 0, 0);
      }
      // D layout: col = lane&15 = pixel (x = tx+m), row = g*4 + j = channel.
      float4 o0, o1;
      o0.x = acc0[0] * scale + bias0.x;  o0.y = acc0[1] * scale + bias0.y;
      o0.z = acc0[2] * scale + bias0.z;  o0.w = acc0[3] * scale + bias0.w;
      o1.x = acc1[0] * scale + bias1.x;  o1.y = acc1[1] * scale + bias1.y;
      o1.z = acc1[2] * scale + bias1.z;  o1.w = acc1[3] * scale + bias1.w;
      float* op = out + (((size_t)((n << 9) + (gy0 + ty)) << 9) + (gx0 + tx + m)) * 32 + (g << 2);
      *(float4*)op = o0;
      *(float4*)(op + 16) = o1;
    }
  }
}

extern "C" void kernel_launch(void* const* d_in, const int* in_sizes, int n_in,
                              void* d_out, int out_size, void* d_ws, size_t ws_size,
                              hipStream_t stream) {
  const float* x = (const float*)d_in[0];
  const float* W = (const float*)d_in[1];
  const float* b = (const float*)d_in[2];
  float* out = (float*)d_out;
  float* ws  = (float*)d_ws;

  prep_kernel<<<1, 256, 0, stream>>>(W, ws);
  conv_kernel<<<4096, 256, 0, stream>>>(x, b, ws, out);
}